// Round 7
// baseline (80.323 us; speedup 1.0000x reference)
//
#include <hip/hip_runtime.h>

#define CHUNK 8
#define NCHUNK 64
#define TDIM 512
#define HW 9216            // 96*96
#define NT 256
#define F4C 2304           // float4 slots per channel
#define K9 9               // f4 slots per thread per channel (2304/256)

typedef float floatx4 __attribute__((ext_vector_type(4)));

__host__ __device__ constexpr int TRI(int c, int j) {       // c<=j incl diag, 36 entries
    return (c*(15-c))/2 + j;
}
__host__ __device__ constexpr int PairIdx(int c, int j) {   // c<j strict, 28 entries
    return 7*c - (c*(c-1))/2 + (j - c - 1);
}

__device__ __forceinline__ unsigned bf16_rne(float f) {
    unsigned u = __float_as_uint(f);
    return (u + 0x7fffu + ((u >> 16) & 1u)) >> 16;   // round-to-nearest-even
}

// Register-resident bf16 stash: each thread holds its 36 px x 8 ch slice as
// 144 packed-bf16 VGPRs. x read from HBM exactly ONCE; no LDS capacity hit,
// so 2 blocks stay resident per CU (the per-block ~12 GB/s streaming cap is
// the empirical wall; 2 blocks -> ~23 GB/s/CU -> ~26 us floor for 151 MB).
__global__ __launch_bounds__(NT, 2)
void lcsap_kernel(const float* __restrict__ x,
                  const float* __restrict__ Wq, const float* __restrict__ bq,
                  const float* __restrict__ Wk, const float* __restrict__ bk,
                  const float* __restrict__ Wv, const float* __restrict__ bv,
                  float* __restrict__ out)
{
    const int bid = blockIdx.x;
    const int b   = bid >> 6;   // batch
    const int n   = bid & 63;   // chunk
    const int tid = threadIdx.x;
    const int lane = tid & 63;
    const int wid  = tid >> 6;

    const float* xb = x + ((size_t)(b*TDIM + n*CHUNK)) * HW;
    float* ob = out + ((size_t)(b*NCHUNK + n)) * HW;

    __shared__ float red[4][44];
    __shared__ float Mld[64];  // M = attn * Wv
    __shared__ float tld[8];   // t = attn * bv
    __shared__ float Gf[64];
    __shared__ float sf[8];

    // ---------------- pass A: stream once, Gram fp32, stash bf16 in regs ----
    float g[36], sr[8];
    #pragma unroll
    for (int i = 0; i < 36; ++i) g[i] = 0.f;
    #pragma unroll
    for (int c = 0; c < 8; ++c) sr[c] = 0.f;

    unsigned d[8][K9][2];      // 144 VGPRs: bf16x2-packed slice

    floatx4 qA[8], qB[8];
    #pragma unroll
    for (int c = 0; c < 8; ++c)
        qA[c] = reinterpret_cast<const floatx4*>(xb + (size_t)c*HW)[tid];

    #pragma unroll
    for (int k = 0; k < K9; ++k) {
        // prefetch next batch into the alternate staging regs
        if (k + 1 < K9) {
            const int fn = tid + (k+1)*NT;
            if (k & 1) {
                #pragma unroll
                for (int c = 0; c < 8; ++c)
                    qA[c] = reinterpret_cast<const floatx4*>(xb + (size_t)c*HW)[fn];
            } else {
                #pragma unroll
                for (int c = 0; c < 8; ++c)
                    qB[c] = reinterpret_cast<const floatx4*>(xb + (size_t)c*HW)[fn];
            }
        }
        // process current batch (k even -> qA, k odd -> qB; k is compile-time)
        #pragma unroll
        for (int c = 0; c < 8; ++c) {
            floatx4 v = (k & 1) ? qB[c] : qA[c];
            #pragma unroll
            for (int u = 0; u < 4; ++u) sr[c] += v[u];
            d[c][k][0] = bf16_rne(v[0]) | (bf16_rne(v[1]) << 16);
            d[c][k][1] = bf16_rne(v[2]) | (bf16_rne(v[3]) << 16);
        }
        #pragma unroll
        for (int u = 0; u < 4; ++u) {
            float xv[8];
            #pragma unroll
            for (int c = 0; c < 8; ++c) xv[c] = (k & 1) ? qB[c][u] : qA[c][u];
            #pragma unroll
            for (int c = 0; c < 8; ++c) {
                #pragma unroll
                for (int j = c; j < 8; ++j)
                    g[TRI(c,j)] += xv[c]*xv[j];
            }
        }
    }

    // wave butterfly reduce
    #pragma unroll
    for (int i = 0; i < 36; ++i) {
        g[i] += __shfl_xor(g[i], 1);  g[i] += __shfl_xor(g[i], 2);
        g[i] += __shfl_xor(g[i], 4);  g[i] += __shfl_xor(g[i], 8);
        g[i] += __shfl_xor(g[i], 16); g[i] += __shfl_xor(g[i], 32);
    }
    #pragma unroll
    for (int c = 0; c < 8; ++c) {
        sr[c] += __shfl_xor(sr[c], 1);  sr[c] += __shfl_xor(sr[c], 2);
        sr[c] += __shfl_xor(sr[c], 4);  sr[c] += __shfl_xor(sr[c], 8);
        sr[c] += __shfl_xor(sr[c], 16); sr[c] += __shfl_xor(sr[c], 32);
    }
    if (lane == 0) {
        #pragma unroll
        for (int i = 0; i < 36; ++i) red[wid][i] = g[i];
        #pragma unroll
        for (int c = 0; c < 8; ++c) red[wid][36+c] = sr[c];
    }
    __syncthreads();
    if (tid < 44) {
        float v = red[0][tid] + red[1][tid] + red[2][tid] + red[3][tid];
        if (tid < 36) {
            int c = 0, base = 0;
            for (; c < 8; ++c) { int w = 8 - c; if (tid < base + w) break; base += w; }
            int j = c + (tid - base);
            Gf[c*8+j] = v;
            Gf[j*8+c] = v;
        } else {
            sf[tid-36] = v;
        }
    }
    __syncthreads();

    // ---------------- tiny 8x8 attention on wave 0 ----------------
    if (tid < 64) {
        const int qi = tid >> 3;
        const int ki = tid & 7;
        float wq[8], wk[8];
        #pragma unroll
        for (int c = 0; c < 8; ++c) {
            wq[c] = Wq[n*64 + qi*8 + c];
            wk[c] = Wk[n*64 + ki*8 + c];
        }
        float sc = 0.f, qs = 0.f, ks_ = 0.f;
        #pragma unroll
        for (int c = 0; c < 8; ++c) {
            float tmp = 0.f;
            #pragma unroll
            for (int dd = 0; dd < 8; ++dd) tmp += Gf[c*8+dd]*wk[dd];
            sc += wq[c]*tmp;
            qs += wq[c]*sf[c];
            ks_ += wk[c]*sf[c];
        }
        const float bqv = bq[n*8+qi];
        const float bkv = bk[n*8+ki];
        sc += qs*bkv + bqv*ks_ + (float)HW * bqv * bkv;
        sc *= (1.0f/96.0f);   // 1/sqrt(9216)

        float m = sc;
        m = fmaxf(m, __shfl_xor(m, 1, 8));
        m = fmaxf(m, __shfl_xor(m, 2, 8));
        m = fmaxf(m, __shfl_xor(m, 4, 8));
        float e = expf(sc - m);
        float se = e;
        se += __shfl_xor(se, 1, 8);
        se += __shfl_xor(se, 2, 8);
        se += __shfl_xor(se, 4, 8);
        const float attn = e / se;

        float mv = 0.f;
        #pragma unroll
        for (int k = 0; k < 8; ++k) {
            float ak = __shfl(attn, k, 8);
            mv += ak * Wv[n*64 + k*8 + ki];
        }
        Mld[qi*8 + ki] = mv;

        float tv = attn * bv[n*8 + ki];
        tv += __shfl_xor(tv, 1, 8);
        tv += __shfl_xor(tv, 2, 8);
        tv += __shfl_xor(tv, 4, 8);
        if (ki == 0) tld[qi] = tv;
    }
    __syncthreads();

    // ---------------- pass B (pure registers): pooled = x^T M x + t^T x -----
    float diag[8], tt[8], su[28];
    #pragma unroll
    for (int c = 0; c < 8; ++c) { diag[c] = Mld[c*9]; tt[c] = tld[c]; }
    #pragma unroll
    for (int c = 0; c < 8; ++c) {
        #pragma unroll
        for (int j = c+1; j < 8; ++j)
            su[PairIdx(c,j)] = Mld[c*8+j] + Mld[j*8+c];
    }

    #pragma unroll
    for (int k = 0; k < K9; ++k) {
        float xv[8][4];
        #pragma unroll
        for (int c = 0; c < 8; ++c) {
            const unsigned w0 = d[c][k][0], w1 = d[c][k][1];
            xv[c][0] = __uint_as_float(w0 << 16);
            xv[c][1] = __uint_as_float(w0 & 0xffff0000u);
            xv[c][2] = __uint_as_float(w1 << 16);
            xv[c][3] = __uint_as_float(w1 & 0xffff0000u);
        }
        floatx4 o;
        #pragma unroll
        for (int u = 0; u < 4; ++u) {
            float acc = 0.f;
            #pragma unroll
            for (int c = 0; c < 8; ++c) acc += tt[c]*xv[c][u];
            #pragma unroll
            for (int c = 0; c < 8; ++c) acc += diag[c]*xv[c][u]*xv[c][u];
            #pragma unroll
            for (int c = 0; c < 8; ++c) {
                #pragma unroll
                for (int j = c+1; j < 8; ++j)
                    acc += su[PairIdx(c,j)]*xv[c][u]*xv[j][u];
            }
            o[u] = acc;
        }
        reinterpret_cast<floatx4*>(ob)[tid + k*NT] = o;
    }
}

extern "C" void kernel_launch(void* const* d_in, const int* in_sizes, int n_in,
                              void* d_out, int out_size, void* d_ws, size_t ws_size,
                              hipStream_t stream) {
    const float* x  = (const float*)d_in[0];
    const float* Wq = (const float*)d_in[1];
    const float* bq = (const float*)d_in[2];
    const float* Wk = (const float*)d_in[3];
    const float* bk = (const float*)d_in[4];
    const float* Wv = (const float*)d_in[5];
    const float* bv = (const float*)d_in[6];
    float* out = (float*)d_out;

    lcsap_kernel<<<dim3(512), dim3(NT), 0, stream>>>(x, Wq, bq, Wk, bk, Wv, bv, out);
}

// Round 8
// 45.764 us; speedup vs baseline: 1.7552x; 1.7552x over previous
//
#include <hip/hip_runtime.h>

#define CHUNK 8
#define NCHUNK 64
#define TDIM 512
#define HW 9216            // 96*96
#define NT 256
#define F4C 2304           // float4 slots per channel
#define ITERS 9            // 2304/256
#define HALF_F4 1152       // f4 slots per channel stashed in LDS (first half)

typedef float floatx4 __attribute__((ext_vector_type(4)));

__host__ __device__ constexpr int TRI(int c, int j) {       // c<=j incl diag, 36 entries
    return (c*(15-c))/2 + j;
}
__host__ __device__ constexpr int PairIdx(int c, int j) {   // c<j strict, 28 entries
    return 7*c - (c*(c-1))/2 + (j - c - 1);
}

__device__ __forceinline__ unsigned bf16_rne(float f) {
    unsigned u = __float_as_uint(f);
    return (u + 0x7fffu + ((u >> 16) & 1u)) >> 16;   // round-to-nearest-even
}

// R0 two-pass structure (2 resident blocks/CU -> dual-tier streaming), plus a
// HALF-chunk bf16 LDS stash (72 KB): pass 2 reads first half from LDS and
// re-reads only the LAST-read half from global (maximal L2 temporal warmth).
// launch_bounds(256,2): VGPR cap 256 -> no spill (R6 lesson); LDS 75.8 KB x 2
// blocks = 152 KB <= 160 -> 2 resident.
__global__ __launch_bounds__(NT, 2)
void lcsap_kernel(const float* __restrict__ x,
                  const float* __restrict__ Wq, const float* __restrict__ bq,
                  const float* __restrict__ Wk, const float* __restrict__ bk,
                  const float* __restrict__ Wv, const float* __restrict__ bv,
                  float* __restrict__ out)
{
    const int bid = blockIdx.x;
    const int b   = bid >> 6;   // batch
    const int n   = bid & 63;   // chunk
    const int tid = threadIdx.x;
    const int lane = tid & 63;
    const int wid  = tid >> 6;

    const float* xb = x + ((size_t)(b*TDIM + n*CHUNK)) * HW;
    float* ob = out + ((size_t)(b*NCHUNK + n)) * HW;

    __shared__ uint2 xs[8][HALF_F4];   // 73728 B bf16x4 stash, first half of pixels
    __shared__ float red[4][44];
    __shared__ float Gf[64];   // full symmetric Gram
    __shared__ float sf[8];    // row sums
    __shared__ float Mld[64];  // M = attn * Wv
    __shared__ float tld[8];   // t = attn * bv

    // ---------------- pass 1: Gram + row sums (fp32), stash first half ------
    float g[36], sr[8];
    #pragma unroll
    for (int i = 0; i < 36; ++i) g[i] = 0.f;
    #pragma unroll
    for (int c = 0; c < 8; ++c) sr[c] = 0.f;

    for (int it = 0; it < ITERS; ++it) {
        const int f = tid + it*NT;
        floatx4 q[8];
        #pragma unroll
        for (int c = 0; c < 8; ++c)
            q[c] = reinterpret_cast<const floatx4*>(xb + (size_t)c*HW)[f];
        if (f < HALF_F4) {   // wave-uniform except iter 4 (waves 0-1 vs 2-3)
            #pragma unroll
            for (int c = 0; c < 8; ++c) {
                uint2 p;
                p.x = bf16_rne(q[c][0]) | (bf16_rne(q[c][1]) << 16);
                p.y = bf16_rne(q[c][2]) | (bf16_rne(q[c][3]) << 16);
                xs[c][f] = p;
            }
        }
        #pragma unroll
        for (int u = 0; u < 4; ++u) {
            float xv[8];
            #pragma unroll
            for (int c = 0; c < 8; ++c) xv[c] = q[c][u];
            #pragma unroll
            for (int c = 0; c < 8; ++c) sr[c] += xv[c];
            #pragma unroll
            for (int c = 0; c < 8; ++c) {
                #pragma unroll
                for (int j = c; j < 8; ++j)
                    g[TRI(c,j)] += xv[c]*xv[j];
            }
        }
    }

    // wave-level butterfly reduce
    #pragma unroll
    for (int i = 0; i < 36; ++i) {
        g[i] += __shfl_xor(g[i], 1);  g[i] += __shfl_xor(g[i], 2);
        g[i] += __shfl_xor(g[i], 4);  g[i] += __shfl_xor(g[i], 8);
        g[i] += __shfl_xor(g[i], 16); g[i] += __shfl_xor(g[i], 32);
    }
    #pragma unroll
    for (int c = 0; c < 8; ++c) {
        sr[c] += __shfl_xor(sr[c], 1);  sr[c] += __shfl_xor(sr[c], 2);
        sr[c] += __shfl_xor(sr[c], 4);  sr[c] += __shfl_xor(sr[c], 8);
        sr[c] += __shfl_xor(sr[c], 16); sr[c] += __shfl_xor(sr[c], 32);
    }
    if (lane == 0) {
        #pragma unroll
        for (int i = 0; i < 36; ++i) red[wid][i] = g[i];
        #pragma unroll
        for (int c = 0; c < 8; ++c) red[wid][36+c] = sr[c];
    }
    __syncthreads();
    if (tid < 44) {
        float v = red[0][tid] + red[1][tid] + red[2][tid] + red[3][tid];
        if (tid < 36) {
            int c = 0, base = 0;
            for (; c < 8; ++c) { int w = 8 - c; if (tid < base + w) break; base += w; }
            int j = c + (tid - base);
            Gf[c*8+j] = v;
            Gf[j*8+c] = v;
        } else {
            sf[tid-36] = v;
        }
    }
    __syncthreads();

    // ---------------- tiny 8x8 attention on wave 0 ----------------
    if (tid < 64) {
        const int qi = tid >> 3;
        const int ki = tid & 7;
        float wq[8], wk[8];
        #pragma unroll
        for (int c = 0; c < 8; ++c) {
            wq[c] = Wq[n*64 + qi*8 + c];
            wk[c] = Wk[n*64 + ki*8 + c];
        }
        float sc = 0.f, qs = 0.f, ks_ = 0.f;
        #pragma unroll
        for (int c = 0; c < 8; ++c) {
            float tmp = 0.f;
            #pragma unroll
            for (int dd = 0; dd < 8; ++dd) tmp += Gf[c*8+dd]*wk[dd];
            sc += wq[c]*tmp;
            qs += wq[c]*sf[c];
            ks_ += wk[c]*sf[c];
        }
        const float bqv = bq[n*8+qi];
        const float bkv = bk[n*8+ki];
        sc += qs*bkv + bqv*ks_ + (float)HW * bqv * bkv;
        sc *= (1.0f/96.0f);   // 1/sqrt(9216)

        float m = sc;
        m = fmaxf(m, __shfl_xor(m, 1, 8));
        m = fmaxf(m, __shfl_xor(m, 2, 8));
        m = fmaxf(m, __shfl_xor(m, 4, 8));
        float e = expf(sc - m);
        float se = e;
        se += __shfl_xor(se, 1, 8);
        se += __shfl_xor(se, 2, 8);
        se += __shfl_xor(se, 4, 8);
        const float attn = e / se;

        float mv = 0.f;
        #pragma unroll
        for (int k = 0; k < 8; ++k) {
            float ak = __shfl(attn, k, 8);
            mv += ak * Wv[n*64 + k*8 + ki];
        }
        Mld[qi*8 + ki] = mv;

        float tv = attn * bv[n*8 + ki];
        tv += __shfl_xor(tv, 1, 8);
        tv += __shfl_xor(tv, 2, 8);
        tv += __shfl_xor(tv, 4, 8);
        if (ki == 0) tld[qi] = tv;
    }
    __syncthreads();

    // ------ pass 2: first half from LDS stash, second half re-read (L2-warm)
    float diag[8], tt[8], su[28];
    #pragma unroll
    for (int c = 0; c < 8; ++c) { diag[c] = Mld[c*9]; tt[c] = tld[c]; }
    #pragma unroll
    for (int c = 0; c < 8; ++c) {
        #pragma unroll
        for (int j = c+1; j < 8; ++j)
            su[PairIdx(c,j)] = Mld[c*8+j] + Mld[j*8+c];
    }

    for (int it = 0; it < ITERS; ++it) {
        const int f = tid + it*NT;
        float xv[8][4];
        if (f < HALF_F4) {
            #pragma unroll
            for (int c = 0; c < 8; ++c) {
                uint2 w = xs[c][f];
                xv[c][0] = __uint_as_float(w.x << 16);
                xv[c][1] = __uint_as_float(w.x & 0xffff0000u);
                xv[c][2] = __uint_as_float(w.y << 16);
                xv[c][3] = __uint_as_float(w.y & 0xffff0000u);
            }
        } else {
            #pragma unroll
            for (int c = 0; c < 8; ++c) {
                floatx4 q = reinterpret_cast<const floatx4*>(xb + (size_t)c*HW)[f];
                xv[c][0] = q[0]; xv[c][1] = q[1]; xv[c][2] = q[2]; xv[c][3] = q[3];
            }
        }
        floatx4 o;
        #pragma unroll
        for (int u = 0; u < 4; ++u) {
            float acc = 0.f;
            #pragma unroll
            for (int c = 0; c < 8; ++c) acc += tt[c]*xv[c][u];
            #pragma unroll
            for (int c = 0; c < 8; ++c) acc += diag[c]*xv[c][u]*xv[c][u];
            #pragma unroll
            for (int c = 0; c < 8; ++c) {
                #pragma unroll
                for (int j = c+1; j < 8; ++j)
                    acc += su[PairIdx(c,j)]*xv[c][u]*xv[j][u];
            }
            o[u] = acc;
        }
        reinterpret_cast<floatx4*>(ob)[f] = o;
    }
}

extern "C" void kernel_launch(void* const* d_in, const int* in_sizes, int n_in,
                              void* d_out, int out_size, void* d_ws, size_t ws_size,
                              hipStream_t stream) {
    const float* x  = (const float*)d_in[0];
    const float* Wq = (const float*)d_in[1];
    const float* bq = (const float*)d_in[2];
    const float* Wk = (const float*)d_in[3];
    const float* bk = (const float*)d_in[4];
    const float* Wv = (const float*)d_in[5];
    const float* bv = (const float*)d_in[6];
    float* out = (float*)d_out;

    lcsap_kernel<<<dim3(512), dim3(NT), 0, stream>>>(x, Wq, bq, Wk, bk, Wv, bv, out);
}